// Round 7
// baseline (168.820 us; speedup 1.0000x reference)
//
#include <hip/hip_runtime.h>
#include <hip/hip_bf16.h>

typedef __bf16 bf16x8 __attribute__((ext_vector_type(8)));
typedef float f32x4 __attribute__((ext_vector_type(4)));
typedef float f32x16 __attribute__((ext_vector_type(16)));
typedef unsigned short u16;
typedef unsigned int u32;

__device__ __forceinline__ u16 f2bf_rne(float f){
  union { float f; u32 u; } v; v.f = f;
  u32 r = v.u + 0x7fffu + ((v.u >> 16) & 1u);
  return (u16)(r >> 16);
}
// pack hi16(a)|hi16(b)<<16 in ONE v_perm_b32 (truncation; P feeds attention weights)
__device__ __forceinline__ u32 pack2(float a, float b){
  return __builtin_amdgcn_perm(__float_as_uint(a), __float_as_uint(b), 0x03020706u);
}
// workgroup barrier WITHOUT vmcnt drain (LDS visibility only): in-flight global
// loads (K reload, V fragments) ride through; compiler vmcnt-waits at their use.
#define BARRIER_LGKM() asm volatile("s_waitcnt lgkmcnt(0)\n\ts_barrier" ::: "memory")

// ---------------- prep: WcatT[320][256] bf16 = [Wh | Wf | Wg]^T ----------------
__global__ __launch_bounds__(256) void prep_kernel(
    const float* __restrict__ Wf, const float* __restrict__ Wg,
    const float* __restrict__ Wh, u16* __restrict__ WcatT){
  __shared__ float tile[32][33];
  const int tx = threadIdx.x & 31, ty = threadIdx.x >> 5;
  const int k0 = blockIdx.x * 32, n0 = blockIdx.y * 32;
  #pragma unroll
  for (int i = 0; i < 4; ++i){
    int k = k0 + ty + i * 8, n = n0 + tx;
    float v;
    if (n < 256)      v = Wh[k * 256 + n];
    else if (n < 288) v = Wf[k * 32 + (n - 256)];
    else              v = Wg[k * 32 + (n - 288)];
    tile[ty + i * 8][tx] = v;
  }
  __syncthreads();
  #pragma unroll
  for (int i = 0; i < 4; ++i){
    int n = n0 + ty + i * 8, k = k0 + tx;
    WcatT[n * 256 + k] = f2bf_rne(tile[tx][ty + i * 8]);
  }
}

// ---------------- projection: h/f/g via MFMA, 512 thr / 8 waves ----------------
// Qg is pre-scaled by log2(e) so flash's softmax needs no fmaf.
// V emitted fragment-major per 64-row group: Vfrag[g64][p_hi(8)][c(256)][j(8)],
// storage position p = p_hi*8+j holds true row tn, p = ((tn&15)<<2)|(tn>>4).
__global__ __launch_bounds__(512) void proj_kernel(
    const float* __restrict__ x, const u16* __restrict__ WcatT,
    u16* __restrict__ Qg, u16* __restrict__ Kg, u16* __restrict__ Vfrag)
{
  __shared__ __align__(16) u16 smem[256 * 72];   // 36 KB, two phases
  u16 (*xb)[264] = (u16(*)[264])smem;
  u16 (*Vr)[72]  = (u16(*)[72])smem;

  const int tid = threadIdx.x;
  const int lane = tid & 63, wave = tid >> 6;
  const int L = lane & 15, quad = lane >> 4;
  const int rowgrp = wave >> 1, colhalf = wave & 1;
  const int n0 = blockIdx.x * 64;

  const float4* xsrc = (const float4*)(x + (size_t)n0 * 256);
  #pragma unroll
  for (int j = 0; j < 8; ++j){
    int idx = j * 512 + tid;
    int row = idx >> 6, col4 = idx & 63;
    float4 v = xsrc[idx];
    u32 p0 = (u32)f2bf_rne(v.x) | ((u32)f2bf_rne(v.y) << 16);
    u32 p1 = (u32)f2bf_rne(v.z) | ((u32)f2bf_rne(v.w) << 16);
    *(uint2*)&xb[row][col4 * 4] = make_uint2(p0, p1);
  }
  __syncthreads();

  f32x4 acc[10];
  #pragma unroll
  for (int cc = 0; cc < 10; ++cc) acc[cc] = (f32x4){0.f, 0.f, 0.f, 0.f};

  #pragma unroll
  for (int kk = 0; kk < 8; ++kk){
    bf16x8 a = *(const bf16x8*)&xb[rowgrp * 16 + L][kk * 32 + quad * 8];
    #pragma unroll
    for (int cc = 0; cc < 10; ++cc){
      int ccg = colhalf * 10 + cc;
      bf16x8 bfr = *(const bf16x8*)(WcatT + (size_t)(ccg * 16 + L) * 256 + kk * 32 + quad * 8);
      acc[cc] = __builtin_amdgcn_mfma_f32_16x16x32_bf16(a, bfr, acc[cc], 0, 0, 0);
    }
  }

  // Qg/Kg: global cc 16..19 (colhalf==1, local 6..9); Qg scaled by log2(e)
  if (colhalf){
    #pragma unroll
    for (int cc = 6; cc < 10; ++cc){
      int ccg = 10 + cc;                                  // 16..19
      u16* dst = (ccg < 18) ? Kg : Qg;                    // K = f, Q = g
      float sc = (ccg < 18) ? 1.0f : 1.44269504088896f;
      int c = (ccg & 1) * 16 + L;
      #pragma unroll
      for (int r = 0; r < 4; ++r){
        int row = n0 + rowgrp * 16 + quad * 4 + r;
        dst[(size_t)row * 32 + c] = f2bf_rne(acc[cc][r] * sc);
      }
    }
  }

  __syncthreads();   // xb consumed; reuse smem as Vr

  {
    const int cmax = colhalf ? 6 : 10;
    for (int cc = 0; cc < cmax; ++cc){
      int ccg = colhalf * 10 + cc;
      int c = ccg * 16 + L;
      #pragma unroll
      for (int r = 0; r < 4; ++r){
        int tn = rowgrp * 16 + quad * 4 + r;
        int p  = ((tn & 15) << 2) | (tn >> 4);
        Vr[c][p] = f2bf_rne(acc[cc][r]);
      }
    }
  }
  __syncthreads();

  u16* Vblk = Vfrag + (size_t)blockIdx.x * (256 * 64);
  #pragma unroll
  for (int i = 0; i < 4; ++i){
    int idx = i * 512 + tid;
    *(uint4*)(Vblk + (size_t)idx * 8) = *(const uint4*)&Vr[idx & 255][(idx >> 8) * 8];
  }
}

// ---------------- flash: 128q x 256c, 8 waves, 2x2 reg blocking, global V ---------
// grid (32 qtiles, 4 batch, 4 splits) x 512 thr, 2 blocks/CU.
// Per kt: QK(kc regs) -> reload kc for kt+1 -> exp/pack/lsum -> P store (dbuf)
//   -> BARRIER_LGKM -> PV: per ks, 2 af (LDS) + 2 vf (global, frag-major, L1/L2)
//      -> 4 MFMAs into 4 f32x16 accs. No end barrier (Plds double-buffered).
__global__ __launch_bounds__(512, 4) void flash_kernel(
    const u16* __restrict__ Qg, const u16* __restrict__ Kg, const u16* __restrict__ Vfrag,
    u16* __restrict__ Opart, float* __restrict__ Lpart)
{
  constexpr float SH = -92.33248261689366f;      // -64*log2(e); s already log2-scaled
  __shared__ __align__(16) u16 Plds[2][128][72]; // 36864 B, double-buffered

  const int tid = threadIdx.x, lane = tid & 63, wave = tid >> 6;
  const int L = lane & 15, quad = lane >> 4;
  const int m32 = lane & 31, h32 = lane >> 5;
  const int wq = wave >> 2, wc = wave & 3;       // PV: wave covers 64q x 64c
  const int b = blockIdx.y, split = blockIdx.z;
  const int qblk = blockIdx.x * 128;

  const u16* Qb = Qg + (size_t)(b * 4096) * 32;
  const u16* Kb = Kg + (size_t)(b * 4096) * 32;
  const u16* Vb = Vfrag + (size_t)b * (64 * 256 * 64);

  const int g0 = split * 16;

  bf16x8 qa = *(const bf16x8*)(Qb + (size_t)(qblk + wave * 16 + L) * 32 + quad * 8);
  const u16* kp0 = Kb + (size_t)(g0 * 64 + L) * 32 + quad * 8;
  bf16x8 kc0 = *(const bf16x8*)(kp0);
  bf16x8 kc1 = *(const bf16x8*)(kp0 + 512);
  bf16x8 kc2 = *(const bf16x8*)(kp0 + 1024);
  bf16x8 kc3 = *(const bf16x8*)(kp0 + 1536);

  f32x16 acc[4];                                  // [qi*2+ci]: 64q x 64c
  #pragma unroll
  for (int t = 0; t < 4; ++t)
    #pragma unroll
    for (int i = 0; i < 16; ++i) acc[t][i] = 0.f;
  float lsum[4] = {0.f, 0.f, 0.f, 0.f};
  const f32x4 zero = (f32x4){0.f, 0.f, 0.f, 0.f};

  for (int kt = 0; kt < 16; ++kt){
    const int g = g0 + kt;
    u16 (*Pw)[72] = Plds[kt & 1];

    // ---- QK^T from registers (s is log2-scaled via Qg) ----
    f32x4 s0 = __builtin_amdgcn_mfma_f32_16x16x32_bf16(qa, kc0, zero, 0, 0, 0);
    f32x4 s1 = __builtin_amdgcn_mfma_f32_16x16x32_bf16(qa, kc1, zero, 0, 0, 0);
    f32x4 s2 = __builtin_amdgcn_mfma_f32_16x16x32_bf16(qa, kc2, zero, 0, 0, 0);
    f32x4 s3 = __builtin_amdgcn_mfma_f32_16x16x32_bf16(qa, kc3, zero, 0, 0, 0);

    // ---- reload kc for kt+1 (kc just consumed; window = exp+barrier+PV) ----
    if (kt < 15){
      const u16* kpn = Kb + (size_t)((g + 1) * 64 + L) * 32 + quad * 8;
      kc0 = *(const bf16x8*)(kpn);
      kc1 = *(const bf16x8*)(kpn + 512);
      kc2 = *(const bf16x8*)(kpn + 1024);
      kc3 = *(const bf16x8*)(kpn + 1536);
    }

    // ---- p = exp2(s+SH); lsum; packed P store (col' = L*4+j) ----
    #pragma unroll
    for (int r = 0; r < 4; ++r){
      float p0 = __builtin_amdgcn_exp2f(s0[r] + SH);
      float p1 = __builtin_amdgcn_exp2f(s1[r] + SH);
      float p2 = __builtin_amdgcn_exp2f(s2[r] + SH);
      float p3 = __builtin_amdgcn_exp2f(s3[r] + SH);
      lsum[r] += (p0 + p1) + (p2 + p3);
      *(uint2*)&Pw[wave * 16 + quad * 4 + r][L * 4] =
          make_uint2(pack2(p0, p1), pack2(p2, p3));
    }

    BARRIER_LGKM();   // P visible; global loads ride through

    // ---- O += P V : per ks, 2 af (LDS) + 2 vf (global, contiguous) -> 4 MFMAs ----
    const u16* Vtile = Vb + (size_t)g * (256 * 64);
    #pragma unroll
    for (int ks = 0; ks < 4; ++ks){
      const u16* vrow = Vtile + (size_t)((ks * 2 + h32) * 256 + wc * 64 + m32) * 8;
      bf16x8 vf0 = *(const bf16x8*)(vrow);
      bf16x8 vf1 = *(const bf16x8*)(vrow + 32 * 8);
      bf16x8 af0 = *(const bf16x8*)&Pw[wq * 64 + m32][ks * 16 + h32 * 8];
      bf16x8 af1 = *(const bf16x8*)&Pw[wq * 64 + 32 + m32][ks * 16 + h32 * 8];
      acc[0] = __builtin_amdgcn_mfma_f32_32x32x16_bf16(af0, vf0, acc[0], 0, 0, 0);
      acc[1] = __builtin_amdgcn_mfma_f32_32x32x16_bf16(af0, vf1, acc[1], 0, 0, 0);
      acc[2] = __builtin_amdgcn_mfma_f32_32x32x16_bf16(af1, vf0, acc[2], 0, 0, 0);
      acc[3] = __builtin_amdgcn_mfma_f32_32x32x16_bf16(af1, vf1, acc[3], 0, 0, 0);
    }
    // no end barrier: Plds double-buffered; next write to this buffer is gated
    // by the NEXT barrier (all waves arrive there only after finishing these reads)
  }

  // ---- epilogue: Opart (bf16, unnormalized), Lpart (fp32) ----
  u16* Ob = Opart + ((size_t)split * 16384 + (size_t)b * 4096 + qblk) * 256;
  #pragma unroll
  for (int t = 0; t < 4; ++t){
    const int qi = t >> 1, ci = t & 1;
    #pragma unroll
    for (int rg = 0; rg < 16; ++rg){
      int row = wq * 64 + qi * 32 + (rg & 3) + 8 * (rg >> 2) + 4 * h32;  // 32x32 C-layout
      int c = wc * 64 + ci * 32 + m32;
      Ob[(size_t)row * 256 + c] = (u16)(__float_as_uint(acc[t][rg]) >> 16);
    }
  }
  #pragma unroll
  for (int r = 0; r < 4; ++r){
    lsum[r] += __shfl_xor(lsum[r], 1);
    lsum[r] += __shfl_xor(lsum[r], 2);
    lsum[r] += __shfl_xor(lsum[r], 4);
    lsum[r] += __shfl_xor(lsum[r], 8);
  }
  if (L == 0){
    float* Lp = Lpart + split * 16384 + b * 4096 + qblk + wave * 16;
    #pragma unroll
    for (int r = 0; r < 4; ++r) Lp[quad * 4 + r] = lsum[r];
  }
}

// ---------------- combine: out = gamma * (sum O_s)/(sum l_s) + x -------------------
__global__ __launch_bounds__(256) void combine_kernel(
    const float* __restrict__ x, const float* __restrict__ gamma,
    const u16* __restrict__ Opart, const float* __restrict__ Lpart,
    float* __restrict__ out)
{
  const int t = threadIdx.x;
  const int row = blockIdx.x * 8 + (t >> 5);
  const int c0 = (t & 31) * 8;
  const size_t base = (size_t)row * 256 + c0;
  float os[8];
  #pragma unroll
  for (int i = 0; i < 8; ++i) os[i] = 0.f;
  float ls = 0.f;
  #pragma unroll
  for (int s = 0; s < 4; ++s){
    ls += Lpart[s * 16384 + row];
    uint4 u = *(const uint4*)(Opart + (size_t)s * 16384 * 256 + base);
    os[0] += __uint_as_float(u.x << 16);
    os[1] += __uint_as_float(u.x & 0xffff0000u);
    os[2] += __uint_as_float(u.y << 16);
    os[3] += __uint_as_float(u.y & 0xffff0000u);
    os[4] += __uint_as_float(u.z << 16);
    os[5] += __uint_as_float(u.z & 0xffff0000u);
    os[6] += __uint_as_float(u.w << 16);
    os[7] += __uint_as_float(u.w & 0xffff0000u);
  }
  const float r = gamma[0] / ls;
  float4 x0 = *(const float4*)(x + base);
  float4 x1 = *(const float4*)(x + base + 4);
  float4 o0, o1;
  o0.x = os[0] * r + x0.x;  o0.y = os[1] * r + x0.y;
  o0.z = os[2] * r + x0.z;  o0.w = os[3] * r + x0.w;
  o1.x = os[4] * r + x1.x;  o1.y = os[5] * r + x1.y;
  o1.z = os[6] * r + x1.z;  o1.w = os[7] * r + x1.w;
  *(float4*)(out + base)     = o0;
  *(float4*)(out + base + 4) = o1;
}

extern "C" void kernel_launch(void* const* d_in, const int* in_sizes, int n_in,
                              void* d_out, int out_size, void* d_ws, size_t ws_size,
                              hipStream_t stream) {
  const float* x     = (const float*)d_in[0];
  const float* Wf    = (const float*)d_in[1];
  const float* Wg    = (const float*)d_in[2];
  const float* Wh    = (const float*)d_in[3];
  const float* gamma = (const float*)d_in[4];
  float* out = (float*)d_out;

  u16* p = (u16*)d_ws;
  u16* Qg    = p;  p += 16384 * 32;               // 1 MB
  u16* Kg    = p;  p += 16384 * 32;               // 1 MB
  u16* Vfrag = p;  p += 4 * 64 * 256 * 64;        // 8 MB, fragment-major
  u16* WcatT = p;  p += 320 * 256;                // 160 KB
  u16* Opart = p;  p += (size_t)4 * 16384 * 256;  // 32 MB
  float* Lpart = (float*)p;                       // 256 KB

  prep_kernel<<<dim3(8, 10), 256, 0, stream>>>(Wf, Wg, Wh, WcatT);
  proj_kernel<<<256, 512, 0, stream>>>(x, WcatT, Qg, Kg, Vfrag);
  flash_kernel<<<dim3(32, 4, 4), 512, 0, stream>>>(Qg, Kg, Vfrag, Opart, Lpart);
  combine_kernel<<<2048, 256, 0, stream>>>(x, gamma, Opart, Lpart, out);
}

// Round 8
// 156.978 us; speedup vs baseline: 1.0754x; 1.0754x over previous
//
#include <hip/hip_runtime.h>
#include <hip/hip_bf16.h>

typedef __bf16 bf16x8 __attribute__((ext_vector_type(8)));
typedef float f32x4 __attribute__((ext_vector_type(4)));
typedef float f32x16 __attribute__((ext_vector_type(16)));
typedef unsigned short u16;
typedef unsigned int u32;

__device__ __forceinline__ u16 f2bf_rne(float f){
  union { float f; u32 u; } v; v.f = f;
  u32 r = v.u + 0x7fffu + ((v.u >> 16) & 1u);
  return (u16)(r >> 16);
}
// pack hi16(a)|hi16(b)<<16 in ONE v_perm_b32 (truncation; P feeds attention weights)
__device__ __forceinline__ u32 pack2(float a, float b){
  return __builtin_amdgcn_perm(__float_as_uint(a), __float_as_uint(b), 0x03020706u);
}
// workgroup barrier WITHOUT vmcnt drain (LDS visibility only): in-flight global
// loads (K/V register prefetches) ride through; compiler vmcnt-waits at use.
#define BARRIER_LGKM() asm volatile("s_waitcnt lgkmcnt(0)\n\ts_barrier" ::: "memory")

// ------------- prep: Wfrag = [Wh|Wf|Wg]^T in MFMA B-fragment order -------------
// Wfrag[cc(20)][kk(8)][lane(64)][j(8)] bf16; lane=(quad,L):
//   element = Wcat[k = kk*32 + quad*8 + j][n = cc*16 + L]
// so proj's B-frag load is 16B/lane fully coalesced (1KB per wave instruction).
__global__ __launch_bounds__(512) void prep_kernel(
    const float* __restrict__ Wf, const float* __restrict__ Wg,
    const float* __restrict__ Wh, u16* __restrict__ Wfrag){
  const int cc = blockIdx.x;             // 20
  const int t = threadIdx.x;             // 512 = kk(8) x lane(64)
  const int kk = t >> 6, lane = t & 63;
  const int L = lane & 15, quad = lane >> 4;
  const int n = cc * 16 + L;
  u32 pk[4];
  #pragma unroll
  for (int j2 = 0; j2 < 4; ++j2){
    float v[2];
    #pragma unroll
    for (int h = 0; h < 2; ++h){
      int k = kk * 32 + quad * 8 + j2 * 2 + h;
      if (n < 256)      v[h] = Wh[k * 256 + n];
      else if (n < 288) v[h] = Wf[k * 32 + (n - 256)];
      else              v[h] = Wg[k * 32 + (n - 288)];
    }
    pk[j2] = (u32)f2bf_rne(v[0]) | ((u32)f2bf_rne(v[1]) << 16);
  }
  uint4* dst = (uint4*)(Wfrag + ((size_t)(cc * 8 + kk) * 64 + lane) * 8);
  *dst = make_uint4(pk[0], pk[1], pk[2], pk[3]);
}

// ---------------- projection: h/f/g via MFMA, 512 thr / 8 waves ----------------
// Qg pre-scaled by log2(e). V emitted fragment-major per 64-row group:
// Vfrag[g64][p_hi(8)][c(256)][j(8)], p = ((tn&15)<<2)|(tn>>4).
__global__ __launch_bounds__(512) void proj_kernel(
    const float* __restrict__ x, const u16* __restrict__ Wfrag,
    u16* __restrict__ Qg, u16* __restrict__ Kg, u16* __restrict__ Vfrag)
{
  __shared__ __align__(16) u16 smem[256 * 72];   // 36 KB, two phases
  u16 (*xb)[264] = (u16(*)[264])smem;
  u16 (*Vr)[72]  = (u16(*)[72])smem;

  const int tid = threadIdx.x;
  const int lane = tid & 63, wave = tid >> 6;
  const int L = lane & 15, quad = lane >> 4;
  const int rowgrp = wave >> 1, colhalf = wave & 1;
  const int n0 = blockIdx.x * 64;

  const float4* xsrc = (const float4*)(x + (size_t)n0 * 256);
  #pragma unroll
  for (int j = 0; j < 8; ++j){
    int idx = j * 512 + tid;
    int row = idx >> 6, col4 = idx & 63;
    float4 v = xsrc[idx];
    u32 p0 = (u32)f2bf_rne(v.x) | ((u32)f2bf_rne(v.y) << 16);
    u32 p1 = (u32)f2bf_rne(v.z) | ((u32)f2bf_rne(v.w) << 16);
    *(uint2*)&xb[row][col4 * 4] = make_uint2(p0, p1);
  }
  __syncthreads();

  f32x4 acc[10];
  #pragma unroll
  for (int cc = 0; cc < 10; ++cc) acc[cc] = (f32x4){0.f, 0.f, 0.f, 0.f};

  #pragma unroll
  for (int kk = 0; kk < 8; ++kk){
    bf16x8 a = *(const bf16x8*)&xb[rowgrp * 16 + L][kk * 32 + quad * 8];
    #pragma unroll
    for (int cc = 0; cc < 10; ++cc){
      int ccg = colhalf * 10 + cc;
      bf16x8 bfr = *(const bf16x8*)(Wfrag + ((size_t)(ccg * 8 + kk) * 64 + lane) * 8);
      acc[cc] = __builtin_amdgcn_mfma_f32_16x16x32_bf16(a, bfr, acc[cc], 0, 0, 0);
    }
  }

  // Qg/Kg: global cc 16..19 (colhalf==1, local 6..9); Qg scaled by log2(e)
  if (colhalf){
    #pragma unroll
    for (int cc = 6; cc < 10; ++cc){
      int ccg = 10 + cc;                                  // 16..19
      u16* dst = (ccg < 18) ? Kg : Qg;                    // K = f, Q = g
      float sc = (ccg < 18) ? 1.0f : 1.44269504088896f;
      int c = (ccg & 1) * 16 + L;
      #pragma unroll
      for (int r = 0; r < 4; ++r){
        int row = n0 + rowgrp * 16 + quad * 4 + r;
        dst[(size_t)row * 32 + c] = f2bf_rne(acc[cc][r] * sc);
      }
    }
  }

  __syncthreads();   // xb consumed; reuse smem as Vr

  {
    const int cmax = colhalf ? 6 : 10;
    for (int cc = 0; cc < cmax; ++cc){
      int ccg = colhalf * 10 + cc;
      int c = ccg * 16 + L;
      #pragma unroll
      for (int r = 0; r < 4; ++r){
        int tn = rowgrp * 16 + quad * 4 + r;
        int p  = ((tn & 15) << 2) | (tn >> 4);
        Vr[c][p] = f2bf_rne(acc[cc][r]);
      }
    }
  }
  __syncthreads();

  u16* Vblk = Vfrag + (size_t)blockIdx.x * (256 * 64);
  #pragma unroll
  for (int i = 0; i < 4; ++i){
    int idx = i * 512 + tid;
    *(uint4*)(Vblk + (size_t)idx * 8) = *(const uint4*)&Vr[idx & 255][(idx >> 8) * 8];
  }
}

// -------- flash: 128q x 256c, 2x2 reg blocking, reg-prefetched K AND V ----------
// 1-D grid 512, XCD swizzle: id&7 -> XCD (heuristic), 2 (b,split) combos per XCD
// so each XCD's L2 holds its 4MB V/K working set. Per kt:
//   QK(kc regs) -> kc(kt+1) reload -> exp/pack/lsum -> P store (dbuf)
//   -> BARRIER_LGKM -> PV: af x2 (LDS) x vfc (regs) -> vfc(kt+1) loads into the
//      SAME regs (WAR resolved at in-order issue; lands during next QK/exp/barrier).
__global__ __launch_bounds__(512) void flash_kernel(
    const u16* __restrict__ Qg, const u16* __restrict__ Kg, const u16* __restrict__ Vfrag,
    u16* __restrict__ Opart, float* __restrict__ Lpart)
{
  constexpr float SH = -92.33248261689366f;      // -64*log2(e); s already log2-scaled
  __shared__ __align__(16) u16 Plds[2][128][72]; // 36864 B, double-buffered

  const int tid = threadIdx.x, lane = tid & 63, wave = tid >> 6;
  const int L = lane & 15, quad = lane >> 4;
  const int m32 = lane & 31, h32 = lane >> 5;
  const int wq = wave >> 2, wc = wave & 3;       // PV: wave covers 64q x 64c

  // XCD-locality swizzle (perf heuristic only)
  const int id = blockIdx.x;                     // 0..511
  const int slot = id >> 3;                      // 0..63
  const int combo = (id & 7) * 2 + (slot >> 5);  // 0..15
  const int qblk = (slot & 31) * 128;
  const int b = combo >> 2, split = combo & 3;

  const u16* Qb = Qg + (size_t)(b * 4096) * 32;
  const u16* Kb = Kg + (size_t)(b * 4096) * 32;
  const u16* Vb = Vfrag + (size_t)b * (64 * 256 * 64);

  const int g0 = split * 16;

  bf16x8 qa = *(const bf16x8*)(Qb + (size_t)(qblk + wave * 16 + L) * 32 + quad * 8);
  const u16* kp0 = Kb + (size_t)(g0 * 64 + L) * 32 + quad * 8;
  bf16x8 kc0 = *(const bf16x8*)(kp0);
  bf16x8 kc1 = *(const bf16x8*)(kp0 + 512);
  bf16x8 kc2 = *(const bf16x8*)(kp0 + 1024);
  bf16x8 kc3 = *(const bf16x8*)(kp0 + 1536);

  // V fragments for current kt, in registers (8 x 16B = 32 VGPRs)
  bf16x8 vfc[8];
  {
    const u16* Vt = Vb + (size_t)g0 * (256 * 64);
    #pragma unroll
    for (int ks = 0; ks < 4; ++ks){
      const u16* vrow = Vt + (size_t)((ks * 2 + h32) * 256 + wc * 64 + m32) * 8;
      vfc[ks * 2]     = *(const bf16x8*)(vrow);
      vfc[ks * 2 + 1] = *(const bf16x8*)(vrow + 32 * 8);
    }
  }

  f32x16 acc[4];                                  // [qi*2+ci]: 64q x 64c
  #pragma unroll
  for (int t = 0; t < 4; ++t)
    #pragma unroll
    for (int i = 0; i < 16; ++i) acc[t][i] = 0.f;
  float lsum[4] = {0.f, 0.f, 0.f, 0.f};
  const f32x4 zero = (f32x4){0.f, 0.f, 0.f, 0.f};

  for (int kt = 0; kt < 16; ++kt){
    const int g = g0 + kt;
    u16 (*Pw)[72] = Plds[kt & 1];

    // ---- QK^T from registers (s is log2-scaled via Qg) ----
    f32x4 s0 = __builtin_amdgcn_mfma_f32_16x16x32_bf16(qa, kc0, zero, 0, 0, 0);
    f32x4 s1 = __builtin_amdgcn_mfma_f32_16x16x32_bf16(qa, kc1, zero, 0, 0, 0);
    f32x4 s2 = __builtin_amdgcn_mfma_f32_16x16x32_bf16(qa, kc2, zero, 0, 0, 0);
    f32x4 s3 = __builtin_amdgcn_mfma_f32_16x16x32_bf16(qa, kc3, zero, 0, 0, 0);

    // ---- kc reload for kt+1 (window = exp + barrier + PV) ----
    if (kt < 15){
      const u16* kpn = Kb + (size_t)((g + 1) * 64 + L) * 32 + quad * 8;
      kc0 = *(const bf16x8*)(kpn);
      kc1 = *(const bf16x8*)(kpn + 512);
      kc2 = *(const bf16x8*)(kpn + 1024);
      kc3 = *(const bf16x8*)(kpn + 1536);
    }

    // ---- p = exp2(s+SH); lsum; packed P store (col' = L*4+j) ----
    #pragma unroll
    for (int r = 0; r < 4; ++r){
      float p0 = __builtin_amdgcn_exp2f(s0[r] + SH);
      float p1 = __builtin_amdgcn_exp2f(s1[r] + SH);
      float p2 = __builtin_amdgcn_exp2f(s2[r] + SH);
      float p3 = __builtin_amdgcn_exp2f(s3[r] + SH);
      lsum[r] += (p0 + p1) + (p2 + p3);
      *(uint2*)&Pw[wave * 16 + quad * 4 + r][L * 4] =
          make_uint2(pack2(p0, p1), pack2(p2, p3));
    }

    BARRIER_LGKM();   // P visible; global prefetches ride through

    // ---- O += P V : af from LDS, vf already in registers ----
    #pragma unroll
    for (int ks = 0; ks < 4; ++ks){
      bf16x8 af0 = *(const bf16x8*)&Pw[wq * 64 + m32][ks * 16 + h32 * 8];
      bf16x8 af1 = *(const bf16x8*)&Pw[wq * 64 + 32 + m32][ks * 16 + h32 * 8];
      acc[0] = __builtin_amdgcn_mfma_f32_32x32x16_bf16(af0, vfc[ks*2],   acc[0], 0, 0, 0);
      acc[1] = __builtin_amdgcn_mfma_f32_32x32x16_bf16(af0, vfc[ks*2+1], acc[1], 0, 0, 0);
      acc[2] = __builtin_amdgcn_mfma_f32_32x32x16_bf16(af1, vfc[ks*2],   acc[2], 0, 0, 0);
      acc[3] = __builtin_amdgcn_mfma_f32_32x32x16_bf16(af1, vfc[ks*2+1], acc[3], 0, 0, 0);
    }

    // ---- vf loads for kt+1 into the same regs (WAR at issue; lands during
    //      next QK/exp/barrier; consumed after barrier(kt+1)) ----
    if (kt < 15){
      const u16* Vn = Vb + (size_t)(g + 1) * (256 * 64);
      #pragma unroll
      for (int ks = 0; ks < 4; ++ks){
        const u16* vrow = Vn + (size_t)((ks * 2 + h32) * 256 + wc * 64 + m32) * 8;
        vfc[ks * 2]     = *(const bf16x8*)(vrow);
        vfc[ks * 2 + 1] = *(const bf16x8*)(vrow + 32 * 8);
      }
    }
    // no end barrier: Plds double-buffered; reuse gated by the next barrier
  }

  // ---- epilogue: Opart (bf16, unnormalized), Lpart (fp32) ----
  u16* Ob = Opart + ((size_t)split * 16384 + (size_t)b * 4096 + qblk) * 256;
  #pragma unroll
  for (int t = 0; t < 4; ++t){
    const int qi = t >> 1, ci = t & 1;
    #pragma unroll
    for (int rg = 0; rg < 16; ++rg){
      int row = wq * 64 + qi * 32 + (rg & 3) + 8 * (rg >> 2) + 4 * h32;  // 32x32 C-layout
      int c = wc * 64 + ci * 32 + m32;
      Ob[(size_t)row * 256 + c] = (u16)(__float_as_uint(acc[t][rg]) >> 16);
    }
  }
  #pragma unroll
  for (int r = 0; r < 4; ++r){
    lsum[r] += __shfl_xor(lsum[r], 1);
    lsum[r] += __shfl_xor(lsum[r], 2);
    lsum[r] += __shfl_xor(lsum[r], 4);
    lsum[r] += __shfl_xor(lsum[r], 8);
  }
  if (L == 0){
    float* Lp = Lpart + split * 16384 + b * 4096 + qblk + wave * 16;
    #pragma unroll
    for (int r = 0; r < 4; ++r) Lp[quad * 4 + r] = lsum[r];
  }
}

// ---------------- combine: out = gamma * (sum O_s)/(sum l_s) + x -------------------
__global__ __launch_bounds__(256) void combine_kernel(
    const float* __restrict__ x, const float* __restrict__ gamma,
    const u16* __restrict__ Opart, const float* __restrict__ Lpart,
    float* __restrict__ out)
{
  const int t = threadIdx.x;
  const int row = blockIdx.x * 8 + (t >> 5);
  const int c0 = (t & 31) * 8;
  const size_t base = (size_t)row * 256 + c0;
  float os[8];
  #pragma unroll
  for (int i = 0; i < 8; ++i) os[i] = 0.f;
  float ls = 0.f;
  #pragma unroll
  for (int s = 0; s < 4; ++s){
    ls += Lpart[s * 16384 + row];
    uint4 u = *(const uint4*)(Opart + (size_t)s * 16384 * 256 + base);
    os[0] += __uint_as_float(u.x << 16);
    os[1] += __uint_as_float(u.x & 0xffff0000u);
    os[2] += __uint_as_float(u.y << 16);
    os[3] += __uint_as_float(u.y & 0xffff0000u);
    os[4] += __uint_as_float(u.z << 16);
    os[5] += __uint_as_float(u.z & 0xffff0000u);
    os[6] += __uint_as_float(u.w << 16);
    os[7] += __uint_as_float(u.w & 0xffff0000u);
  }
  const float r = gamma[0] / ls;
  float4 x0 = *(const float4*)(x + base);
  float4 x1 = *(const float4*)(x + base + 4);
  float4 o0, o1;
  o0.x = os[0] * r + x0.x;  o0.y = os[1] * r + x0.y;
  o0.z = os[2] * r + x0.z;  o0.w = os[3] * r + x0.w;
  o1.x = os[4] * r + x1.x;  o1.y = os[5] * r + x1.y;
  o1.z = os[6] * r + x1.z;  o1.w = os[7] * r + x1.w;
  *(float4*)(out + base)     = o0;
  *(float4*)(out + base + 4) = o1;
}

extern "C" void kernel_launch(void* const* d_in, const int* in_sizes, int n_in,
                              void* d_out, int out_size, void* d_ws, size_t ws_size,
                              hipStream_t stream) {
  const float* x     = (const float*)d_in[0];
  const float* Wf    = (const float*)d_in[1];
  const float* Wg    = (const float*)d_in[2];
  const float* Wh    = (const float*)d_in[3];
  const float* gamma = (const float*)d_in[4];
  float* out = (float*)d_out;

  u16* p = (u16*)d_ws;
  u16* Qg    = p;  p += 16384 * 32;               // 1 MB
  u16* Kg    = p;  p += 16384 * 32;               // 1 MB
  u16* Vfrag = p;  p += 4 * 64 * 256 * 64;        // 8 MB, fragment-major
  u16* Wfrag = p;  p += 20 * 8 * 64 * 8;          // 160 KB, fragment-major
  u16* Opart = p;  p += (size_t)4 * 16384 * 256;  // 32 MB
  float* Lpart = (float*)p;                       // 256 KB

  prep_kernel<<<20, 512, 0, stream>>>(Wf, Wg, Wh, Wfrag);
  proj_kernel<<<256, 512, 0, stream>>>(x, Wfrag, Qg, Kg, Vfrag);
  flash_kernel<<<512, 512, 0, stream>>>(Qg, Kg, Vfrag, Opart, Lpart);
  combine_kernel<<<2048, 256, 0, stream>>>(x, gamma, Opart, Lpart, out);
}

// Round 9
// 149.320 us; speedup vs baseline: 1.1306x; 1.0513x over previous
//
#include <hip/hip_runtime.h>
#include <hip/hip_bf16.h>

typedef __bf16 bf16x8 __attribute__((ext_vector_type(8)));
typedef float f32x4 __attribute__((ext_vector_type(4)));
typedef float f32x16 __attribute__((ext_vector_type(16)));
typedef unsigned short u16;
typedef unsigned int u32;

__device__ __forceinline__ u16 f2bf_rne(float f){
  union { float f; u32 u; } v; v.f = f;
  u32 r = v.u + 0x7fffu + ((v.u >> 16) & 1u);
  return (u16)(r >> 16);
}
// pack hi16(a)|hi16(b)<<16 in ONE v_perm_b32 (truncation; P feeds attention weights)
__device__ __forceinline__ u32 pack2(float a, float b){
  return __builtin_amdgcn_perm(__float_as_uint(a), __float_as_uint(b), 0x03020706u);
}
// workgroup barrier WITHOUT vmcnt drain (LDS visibility only): in-flight global
// loads (K/V register prefetches) ride through; compiler vmcnt-waits at use.
#define BARRIER_LGKM() asm volatile("s_waitcnt lgkmcnt(0)\n\ts_barrier" ::: "memory")

// ------------- prep: Wfrag = [Wh|Wf|Wg]^T in MFMA B-fragment order -------------
// Wfrag[cc(20)][kk(8)][lane(64)][j(8)] bf16; lane=(quad,L):
//   element = Wcat[k = kk*32 + quad*8 + j][n = cc*16 + L]
__global__ __launch_bounds__(512) void prep_kernel(
    const float* __restrict__ Wf, const float* __restrict__ Wg,
    const float* __restrict__ Wh, u16* __restrict__ Wfrag){
  const int cc = blockIdx.x;             // 20
  const int t = threadIdx.x;             // 512 = kk(8) x lane(64)
  const int kk = t >> 6, lane = t & 63;
  const int L = lane & 15, quad = lane >> 4;
  const int n = cc * 16 + L;
  u32 pk[4];
  #pragma unroll
  for (int j2 = 0; j2 < 4; ++j2){
    float v[2];
    #pragma unroll
    for (int h = 0; h < 2; ++h){
      int k = kk * 32 + quad * 8 + j2 * 2 + h;
      if (n < 256)      v[h] = Wh[k * 256 + n];
      else if (n < 288) v[h] = Wf[k * 32 + (n - 256)];
      else              v[h] = Wg[k * 32 + (n - 288)];
    }
    pk[j2] = (u32)f2bf_rne(v[0]) | ((u32)f2bf_rne(v[1]) << 16);
  }
  uint4* dst = (uint4*)(Wfrag + ((size_t)(cc * 8 + kk) * 64 + lane) * 8);
  *dst = make_uint4(pk[0], pk[1], pk[2], pk[3]);
}

// ---------------- projection: h/f/g via MFMA, 512 thr / 8 waves ----------------
// Qg pre-scaled by log2(e). V emitted fragment-major per 64-row group:
// Vfrag[g64][p_hi(8)][c(256)][j(8)], p = ((tn&15)<<2)|(tn>>4).
__global__ __launch_bounds__(512) void proj_kernel(
    const float* __restrict__ x, const u16* __restrict__ Wfrag,
    u16* __restrict__ Qg, u16* __restrict__ Kg, u16* __restrict__ Vfrag)
{
  __shared__ __align__(16) u16 smem[256 * 72];   // 36 KB, two phases
  u16 (*xb)[264] = (u16(*)[264])smem;
  u16 (*Vr)[72]  = (u16(*)[72])smem;

  const int tid = threadIdx.x;
  const int lane = tid & 63, wave = tid >> 6;
  const int L = lane & 15, quad = lane >> 4;
  const int rowgrp = wave >> 1, colhalf = wave & 1;
  const int n0 = blockIdx.x * 64;

  const float4* xsrc = (const float4*)(x + (size_t)n0 * 256);
  #pragma unroll
  for (int j = 0; j < 8; ++j){
    int idx = j * 512 + tid;
    int row = idx >> 6, col4 = idx & 63;
    float4 v = xsrc[idx];
    u32 p0 = (u32)f2bf_rne(v.x) | ((u32)f2bf_rne(v.y) << 16);
    u32 p1 = (u32)f2bf_rne(v.z) | ((u32)f2bf_rne(v.w) << 16);
    *(uint2*)&xb[row][col4 * 4] = make_uint2(p0, p1);
  }
  __syncthreads();

  f32x4 acc[10];
  #pragma unroll
  for (int cc = 0; cc < 10; ++cc) acc[cc] = (f32x4){0.f, 0.f, 0.f, 0.f};

  #pragma unroll
  for (int kk = 0; kk < 8; ++kk){
    bf16x8 a = *(const bf16x8*)&xb[rowgrp * 16 + L][kk * 32 + quad * 8];
    #pragma unroll
    for (int cc = 0; cc < 10; ++cc){
      int ccg = colhalf * 10 + cc;
      bf16x8 bfr = *(const bf16x8*)(Wfrag + ((size_t)(ccg * 8 + kk) * 64 + lane) * 8);
      acc[cc] = __builtin_amdgcn_mfma_f32_16x16x32_bf16(a, bfr, acc[cc], 0, 0, 0);
    }
  }

  if (colhalf){
    #pragma unroll
    for (int cc = 6; cc < 10; ++cc){
      int ccg = 10 + cc;                                  // 16..19
      u16* dst = (ccg < 18) ? Kg : Qg;                    // K = f, Q = g
      float sc = (ccg < 18) ? 1.0f : 1.44269504088896f;
      int c = (ccg & 1) * 16 + L;
      #pragma unroll
      for (int r = 0; r < 4; ++r){
        int row = n0 + rowgrp * 16 + quad * 4 + r;
        dst[(size_t)row * 32 + c] = f2bf_rne(acc[cc][r] * sc);
      }
    }
  }

  __syncthreads();   // xb consumed; reuse smem as Vr

  {
    const int cmax = colhalf ? 6 : 10;
    for (int cc = 0; cc < cmax; ++cc){
      int ccg = colhalf * 10 + cc;
      int c = ccg * 16 + L;
      #pragma unroll
      for (int r = 0; r < 4; ++r){
        int tn = rowgrp * 16 + quad * 4 + r;
        int p  = ((tn & 15) << 2) | (tn >> 4);
        Vr[c][p] = f2bf_rne(acc[cc][r]);
      }
    }
  }
  __syncthreads();

  u16* Vblk = Vfrag + (size_t)blockIdx.x * (256 * 64);
  #pragma unroll
  for (int i = 0; i < 4; ++i){
    int idx = i * 512 + tid;
    *(uint4*)(Vblk + (size_t)idx * 8) = *(const uint4*)&Vr[idx & 255][(idx >> 8) * 8];
  }
}

// ------- flash: q-tile 64, 8 waves = 2 internal k-halves, fused epilogue --------
// grid 256 x 512 thr, 1 block/CU. half = wave>>2 sweeps k in [half*2048, +2048)
// (32 groups of 64) with its own double-buffered Plds; wv = wave&3.
// QK: wave = 16 q-rows x 64 k (4 MFMA). PV: wave = 64q x 64c (wc=wv), vf in regs.
// Epilogue: halves merge via LDS Osh (overlays Plds), l via Lsh, then
// out = gamma*O/l + x written fully coalesced. No Opart/Lpart/combine.
__global__ __launch_bounds__(512) void flash_kernel(
    const u16* __restrict__ Qg, const u16* __restrict__ Kg, const u16* __restrict__ Vfrag,
    const float* __restrict__ x, const float* __restrict__ gamma, float* __restrict__ out)
{
  constexpr float SH = -92.33248261689366f;      // -64*log2(e); s already log2-scaled
  __shared__ __align__(16) char smem[65536];     // Plds 36864 B overlaid by Osh 64 KB
  u16 (*Plds)[2][64][72] = (u16 (*)[2][64][72])smem;  // [half][buf][row][72]
  float (*Osh)[256] = (float (*)[256])smem;
  __shared__ float Lsh[2][64];

  const int tid = threadIdx.x, lane = tid & 63, wave = tid >> 6;
  const int L = lane & 15, quad = lane >> 4;
  const int m32 = lane & 31, h32 = lane >> 5;
  const int half = wave >> 2, wv = wave & 3;

  // XCD swizzle: id&7 -> XCD; 2 XCDs per batch (V+K+Q working set ~2.5MB < 4MB L2)
  const int id = blockIdx.x;                     // 0..255
  const int xcd = id & 7;
  const int b = xcd >> 1;
  const int qt = (xcd & 1) * 32 + (id >> 3);     // 0..63
  const int q0 = qt * 64;

  const u16* Qb = Qg + (size_t)(b * 4096) * 32;
  const u16* Kb = Kg + (size_t)(b * 4096) * 32;
  const u16* Vb = Vfrag + (size_t)b * (64 * 256 * 64);
  const float gm = gamma[0];

  const int g0 = half * 32;

  bf16x8 qa = *(const bf16x8*)(Qb + (size_t)(q0 + wv * 16 + L) * 32 + quad * 8);
  const u16* kp0 = Kb + (size_t)(g0 * 64 + L) * 32 + quad * 8;
  bf16x8 kc0 = *(const bf16x8*)(kp0);
  bf16x8 kc1 = *(const bf16x8*)(kp0 + 512);
  bf16x8 kc2 = *(const bf16x8*)(kp0 + 1024);
  bf16x8 kc3 = *(const bf16x8*)(kp0 + 1536);

  bf16x8 vfc[8];
  {
    const u16* Vt = Vb + (size_t)g0 * (256 * 64);
    #pragma unroll
    for (int ks = 0; ks < 4; ++ks){
      const u16* vrow = Vt + (size_t)((ks * 2 + h32) * 256 + wv * 64 + m32) * 8;
      vfc[ks * 2]     = *(const bf16x8*)(vrow);
      vfc[ks * 2 + 1] = *(const bf16x8*)(vrow + 32 * 8);
    }
  }

  f32x16 acc[4];                                  // [qi*2+ci]: 64q x 64c
  #pragma unroll
  for (int t = 0; t < 4; ++t)
    #pragma unroll
    for (int i = 0; i < 16; ++i) acc[t][i] = 0.f;
  float lsum[4] = {0.f, 0.f, 0.f, 0.f};
  const f32x4 zero = (f32x4){0.f, 0.f, 0.f, 0.f};

  for (int kt = 0; kt < 32; ++kt){
    const int g = g0 + kt;
    u16 (*Pw)[72] = Plds[half][kt & 1];

    // ---- QK^T from registers (s log2-scaled via Qg) ----
    f32x4 s0 = __builtin_amdgcn_mfma_f32_16x16x32_bf16(qa, kc0, zero, 0, 0, 0);
    f32x4 s1 = __builtin_amdgcn_mfma_f32_16x16x32_bf16(qa, kc1, zero, 0, 0, 0);
    f32x4 s2 = __builtin_amdgcn_mfma_f32_16x16x32_bf16(qa, kc2, zero, 0, 0, 0);
    f32x4 s3 = __builtin_amdgcn_mfma_f32_16x16x32_bf16(qa, kc3, zero, 0, 0, 0);

    // ---- kc reload for kt+1 (window = exp + barrier + PV) ----
    if (kt < 31){
      const u16* kpn = Kb + (size_t)((g + 1) * 64 + L) * 32 + quad * 8;
      kc0 = *(const bf16x8*)(kpn);
      kc1 = *(const bf16x8*)(kpn + 512);
      kc2 = *(const bf16x8*)(kpn + 1024);
      kc3 = *(const bf16x8*)(kpn + 1536);
    }

    // ---- p = exp2(s+SH); lsum; packed P store (col' = L*4+j) ----
    #pragma unroll
    for (int r = 0; r < 4; ++r){
      float p0 = __builtin_amdgcn_exp2f(s0[r] + SH);
      float p1 = __builtin_amdgcn_exp2f(s1[r] + SH);
      float p2 = __builtin_amdgcn_exp2f(s2[r] + SH);
      float p3 = __builtin_amdgcn_exp2f(s3[r] + SH);
      lsum[r] += (p0 + p1) + (p2 + p3);
      *(uint2*)&Pw[wv * 16 + quad * 4 + r][L * 4] =
          make_uint2(pack2(p0, p1), pack2(p2, p3));
    }

    BARRIER_LGKM();   // P visible; global prefetches ride through

    // ---- O += P V : af from own half's Plds, vf already in registers ----
    #pragma unroll
    for (int ks = 0; ks < 4; ++ks){
      bf16x8 af0 = *(const bf16x8*)&Pw[m32][ks * 16 + h32 * 8];
      bf16x8 af1 = *(const bf16x8*)&Pw[32 + m32][ks * 16 + h32 * 8];
      acc[0] = __builtin_amdgcn_mfma_f32_32x32x16_bf16(af0, vfc[ks*2],   acc[0], 0, 0, 0);
      acc[1] = __builtin_amdgcn_mfma_f32_32x32x16_bf16(af0, vfc[ks*2+1], acc[1], 0, 0, 0);
      acc[2] = __builtin_amdgcn_mfma_f32_32x32x16_bf16(af1, vfc[ks*2],   acc[2], 0, 0, 0);
      acc[3] = __builtin_amdgcn_mfma_f32_32x32x16_bf16(af1, vfc[ks*2+1], acc[3], 0, 0, 0);
    }

    // ---- vf loads for kt+1 into the same regs (consumed after next barrier) ----
    if (kt < 31){
      const u16* Vn = Vb + (size_t)(g + 1) * (256 * 64);
      #pragma unroll
      for (int ks = 0; ks < 4; ++ks){
        const u16* vrow = Vn + (size_t)((ks * 2 + h32) * 256 + wv * 64 + m32) * 8;
        vfc[ks * 2]     = *(const bf16x8*)(vrow);
        vfc[ks * 2 + 1] = *(const bf16x8*)(vrow + 32 * 8);
      }
    }
    // no end barrier: per-half Plds double-buffered; reuse gated by next barrier
  }

  // ================= fused epilogue =================
  BARRIER_LGKM();   // all PV ds-reads retired; Plds region reusable as Osh

  // l: reduce 16 partial lanes per (quad,r); rows wv*16+quad*4+r of this half
  #pragma unroll
  for (int r = 0; r < 4; ++r){
    lsum[r] += __shfl_xor(lsum[r], 1);
    lsum[r] += __shfl_xor(lsum[r], 2);
    lsum[r] += __shfl_xor(lsum[r], 4);
    lsum[r] += __shfl_xor(lsum[r], 8);
  }
  if (L == 0){
    #pragma unroll
    for (int r = 0; r < 4; ++r) Lsh[half][wv * 16 + quad * 4 + r] = lsum[r];
  }
  // half 1 deposits its accumulator into Osh (fp32)
  if (half == 1){
    #pragma unroll
    for (int t = 0; t < 4; ++t){
      const int qi = t >> 1, ci = t & 1;
      #pragma unroll
      for (int rg = 0; rg < 16; ++rg){
        int row = qi * 32 + (rg & 3) + 8 * (rg >> 2) + 4 * h32;   // 32x32 C-layout
        Osh[row][wv * 64 + ci * 32 + m32] = acc[t][rg];
      }
    }
  }
  __syncthreads();
  if (wave == 0){   // per-row scale factor gamma / (l0 + l1)
    float li = gm / (Lsh[0][lane] + Lsh[1][lane]);
    Lsh[0][lane] = li;
  }
  __syncthreads();
  // half 0 merges, scales, writes back to Osh
  if (half == 0){
    #pragma unroll
    for (int t = 0; t < 4; ++t){
      const int qi = t >> 1, ci = t & 1;
      #pragma unroll
      for (int rg = 0; rg < 16; ++rg){
        int row = qi * 32 + (rg & 3) + 8 * (rg >> 2) + 4 * h32;
        int col = wv * 64 + ci * 32 + m32;
        Osh[row][col] = (acc[t][rg] + Osh[row][col]) * Lsh[0][row];
      }
    }
  }
  __syncthreads();
  // coalesced: out = Osh + x
  const size_t base = ((size_t)(b * 4096) + q0) * 256;
  const float4* xs = (const float4*)(x + base);
  float4* od = (float4*)(out + base);
  const float4* Of = (const float4*)&Osh[0][0];
  #pragma unroll
  for (int i = 0; i < 8; ++i){
    int idx = i * 512 + tid;
    float4 o = Of[idx], xv = xs[idx];
    o.x += xv.x; o.y += xv.y; o.z += xv.z; o.w += xv.w;
    od[idx] = o;
  }
}

extern "C" void kernel_launch(void* const* d_in, const int* in_sizes, int n_in,
                              void* d_out, int out_size, void* d_ws, size_t ws_size,
                              hipStream_t stream) {
  const float* x     = (const float*)d_in[0];
  const float* Wf    = (const float*)d_in[1];
  const float* Wg    = (const float*)d_in[2];
  const float* Wh    = (const float*)d_in[3];
  const float* gamma = (const float*)d_in[4];
  float* out = (float*)d_out;

  u16* p = (u16*)d_ws;
  u16* Qg    = p;  p += 16384 * 32;               // 1 MB
  u16* Kg    = p;  p += 16384 * 32;               // 1 MB
  u16* Vfrag = p;  p += 4 * 64 * 256 * 64;        // 8 MB, fragment-major
  u16* Wfrag = p;  p += 20 * 8 * 64 * 8;          // 160 KB, fragment-major

  prep_kernel<<<20, 512, 0, stream>>>(Wf, Wg, Wh, Wfrag);
  proj_kernel<<<256, 512, 0, stream>>>(x, Wfrag, Qg, Kg, Vfrag);
  flash_kernel<<<256, 512, 0, stream>>>(Qg, Kg, Vfrag, x, gamma, out);
}